// Round 1
// baseline (515.851 us; speedup 1.0000x reference)
//
#include <hip/hip_runtime.h>
#include <hip/hip_bf16.h>

// Problem constants (B,N,C,NF) = (4,512,128,96)
#define NB 4
#define NN 512
#define CC 128

typedef __bf16 bf16x8 __attribute__((ext_vector_type(8)));
typedef __bf16 bf16x4 __attribute__((ext_vector_type(4)));
typedef float  f32x4  __attribute__((ext_vector_type(4)));

// ---------------- fp32 -> bf16 conversion prepass ----------------
__global__ void cvt_bf16(const float* __restrict__ s, __bf16* __restrict__ d, int n4) {
    int idx = blockIdx.x * blockDim.x + threadIdx.x;
    if (idx < n4) {
        float4 v = ((const float4*)s)[idx];
        bf16x4 o = { (__bf16)v.x, (__bf16)v.y, (__bf16)v.z, (__bf16)v.w };
        ((bf16x4*)d)[idx] = o;
    }
}

// ---------------- one MLP layer via MFMA ----------------
// in : LDS, [64 rows][KIN] bf16, row stride SIN (padded, multiple of 8)
// out: LDS, [64 rows][NOUT] bf16, row stride SOUT
// w  : global bf16, row-major [NOUT][KIN]  (== B^T: B[k][n] = w[n][k])
// WIDE  (NOUT=192): wave w owns n-chunks {w, w+4, w+8}, all 4 m-chunks
// !WIDE (NOUT= 96): wave w owns n-chunks {3*(w&1)+0,1,2}, m-chunks (w>>1)*2..+2
// 3 simultaneous accumulators per wave => 1 a-frag LDS read per 3 MFMAs.
template<int KIN, int SIN, int SOUT, bool WIDE>
__device__ __forceinline__ void mlp_layer(const __bf16* in, __bf16* outb,
                                          const __bf16* __restrict__ w,
                                          const float* __restrict__ bias,
                                          int lane, int wave)
{
    constexpr int KC = KIN / 32;
    int nc0, nstep, mlo, mhi;
    if (WIDE) { nc0 = wave;          nstep = 4; mlo = 0;               mhi = 4; }
    else      { nc0 = (wave & 1)*3;  nstep = 1; mlo = (wave >> 1)*2;   mhi = mlo + 2; }
    const int l15 = lane & 15;
    const int q8  = (lane >> 4) * 8;

    // B fragments: B[k=kc*32+q8+j][n=nc*16+l15] = w[n][k] -> 16B contiguous load
    bf16x8 bfr[3][KC];
    float  bv[3];
#pragma unroll
    for (int u = 0; u < 3; ++u) {
        const int n = (nc0 + u * nstep) * 16 + l15;
        bv[u] = bias[n];
#pragma unroll
        for (int k = 0; k < KC; ++k)
            bfr[u][k] = *(const bf16x8*)(w + (size_t)n * KIN + k * 32 + q8);
    }

    for (int m = mlo; m < mhi; ++m) {
        f32x4 acc[3];
#pragma unroll
        for (int u = 0; u < 3; ++u) acc[u] = (f32x4){bv[u], bv[u], bv[u], bv[u]};
#pragma unroll
        for (int k = 0; k < KC; ++k) {
            // A[m=l15][k=q8+j] from LDS (stride padded => balanced banks)
            bf16x8 a = *(const bf16x8*)(in + (m * 16 + l15) * SIN + k * 32 + q8);
#pragma unroll
            for (int u = 0; u < 3; ++u)
                acc[u] = __builtin_amdgcn_mfma_f32_16x16x32_bf16(a, bfr[u][k], acc[u], 0, 0, 0);
        }
        // C/D: col = lane&15 (n), row = (lane>>4)*4 + reg (m)   [verified m89/m91]
        const int rowb = m * 16 + (lane >> 4) * 4;
#pragma unroll
        for (int u = 0; u < 3; ++u) {
            const int n = (nc0 + u * nstep) * 16 + l15;
#pragma unroll
            for (int r = 0; r < 4; ++r) {
                float v = acc[u][r] ;
                v = v > 0.f ? v : 0.01f * v;       // leaky relu
                outb[(rowb + r) * SOUT + n] = (__bf16)v;
            }
        }
    }
}

// ---------------- fused edge-MLP kernel ----------------
// block: 64 edges = 4 i-rows x 16 j, 256 threads (4 waves)
// LDS arenas ping-pong: d(136) -> h1(200) -> h2(200) -> h3(104) -> h4(104)
__global__ __launch_bounds__(256, 3) void mlp_edges(
    const __bf16* __restrict__ xb,
    const __bf16* __restrict__ w1b, const float* __restrict__ b1,
    const __bf16* __restrict__ w2b, const float* __restrict__ b2,
    const __bf16* __restrict__ w3b, const float* __restrict__ b3,
    const __bf16* __restrict__ w4b, const float* __restrict__ b4,
    const float* __restrict__ w5,  const float* __restrict__ b5,
    float* __restrict__ out)
{
    __shared__ __align__(16) __bf16 Abuf[64 * 200];
    __shared__ __align__(16) __bf16 Bbuf[64 * 200];
    __shared__ float red[256];

    const int t    = threadIdx.x;
    const int lane = t & 63;
    const int wave = t >> 6;
    const int j0 = blockIdx.x * 16;
    const int i0 = blockIdx.y * 4;
    const int b  = blockIdx.z;

    // ---- stage d = |x_i - x_j| into Abuf (stride 136) as bf16 ----
    {
        const int m  = t >> 2;            // edge row 0..63; i = m>>4, j = m&15
        const int c0 = (t & 3) * 32;
        const __bf16* xi = xb + ((size_t)b * NN + (i0 + (m >> 4))) * CC;
        const __bf16* xj = xb + ((size_t)b * NN + (j0 + (m & 15))) * CC;
#pragma unroll
        for (int c = 0; c < 32; c += 8) {
            bf16x8 a  = *(const bf16x8*)(xi + c0 + c);
            bf16x8 bj = *(const bf16x8*)(xj + c0 + c);
            bf16x8 dd;
#pragma unroll
            for (int u = 0; u < 8; ++u) {
                float v = (float)a[u] - (float)bj[u];
                dd[u] = (__bf16)fabsf(v);
            }
            *(bf16x8*)(&Abuf[m * 136 + c0 + c]) = dd;
        }
    }
    __syncthreads();
    mlp_layer<128, 136, 200, true >(Abuf, Bbuf, w1b, b1, lane, wave);  // d  -> h1
    __syncthreads();
    mlp_layer<192, 200, 200, true >(Bbuf, Abuf, w2b, b2, lane, wave);  // h1 -> h2
    __syncthreads();
    mlp_layer<192, 200, 104, false>(Abuf, Bbuf, w3b, b3, lane, wave);  // h2 -> h3
    __syncthreads();
    mlp_layer< 96, 104, 104, false>(Bbuf, Abuf, w4b, b4, lane, wave);  // h3 -> h4
    __syncthreads();

    // ---- layer 5: logit = h4 . w5 + b5 (VALU), write to out[...,1] ----
    {
        const int e    = t & 63;
        const int part = t >> 6;          // 4 partials of 24
        float s = 0.f;
#pragma unroll
        for (int k = 0; k < 24; ++k)
            s += (float)Abuf[e * 104 + part * 24 + k] * w5[part * 24 + k];
        red[t] = s;
    }
    __syncthreads();
    if (t < 64) {
        const float logit = red[t] + red[t + 64] + red[t + 128] + red[t + 192] + b5[0];
        const int i = i0 + (t >> 4);
        const int j = j0 + (t & 15);
        out[(((size_t)b * NN + i) * NN + j) * 2 + 1] = logit;
    }
}

// ---------------- softmax over j per (b,i) row, in place on out ----------------
__global__ __launch_bounds__(256) void softmax_rows(float* __restrict__ out)
{
    const int row = blockIdx.x;           // b*512 + i
    const int i   = row & (NN - 1);
    float* base = out + (size_t)row * (NN * 2);
    const int t = threadIdx.x;

    float v0 = base[t * 2 + 1];
    float v1 = base[(t + 256) * 2 + 1];
    if (t == i)       v0 = -__builtin_inff();   // self-edge mask (logit - 1e8 -> exp = 0)
    if (t + 256 == i) v1 = -__builtin_inff();

    float mx = fmaxf(v0, v1);
#pragma unroll
    for (int off = 32; off; off >>= 1) mx = fmaxf(mx, __shfl_xor(mx, off, 64));
    __shared__ float sm[4], ss[4];
    const int wave = t >> 6, lane = t & 63;
    if (lane == 0) sm[wave] = mx;
    __syncthreads();
    mx = fmaxf(fmaxf(sm[0], sm[1]), fmaxf(sm[2], sm[3]));

    const float e0 = __expf(v0 - mx), e1 = __expf(v1 - mx);
    float s = e0 + e1;
#pragma unroll
    for (int off = 32; off; off >>= 1) s += __shfl_xor(s, off, 64);
    if (lane == 0) ss[wave] = s;
    __syncthreads();
    s = ss[0] + ss[1] + ss[2] + ss[3];
    const float inv = 1.0f / s;

    float2* o2 = (float2*)base;
    o2[t]       = make_float2(t == i ? 1.f : 0.f,         e0 * inv);
    o2[t + 256] = make_float2((t + 256) == i ? 1.f : 0.f, e1 * inv);
}

// ---------------- host launch ----------------
extern "C" void kernel_launch(void* const* d_in, const int* in_sizes, int n_in,
                              void* d_out, int out_size, void* d_ws, size_t ws_size,
                              hipStream_t stream) {
    const float* x  = (const float*)d_in[0];
    // d_in[1] = W_id (pure eye broadcast; synthesized in-kernel)
    const float* w1 = (const float*)d_in[2];
    const float* b1 = (const float*)d_in[3];
    const float* w2 = (const float*)d_in[4];
    const float* b2 = (const float*)d_in[5];
    const float* w3 = (const float*)d_in[6];
    const float* b3 = (const float*)d_in[7];
    const float* w4 = (const float*)d_in[8];
    const float* b4 = (const float*)d_in[9];
    const float* w5 = (const float*)d_in[10];
    const float* b5 = (const float*)d_in[11];
    float* out = (float*)d_out;

    // ws layout (bf16): x 524288B | w1 49152B | w2 73728B | w3 36864B | w4 18432B
    char* ws = (char*)d_ws;
    __bf16* xb  = (__bf16*)(ws);
    __bf16* w1b = (__bf16*)(ws + 524288);
    __bf16* w2b = (__bf16*)(ws + 573440);
    __bf16* w3b = (__bf16*)(ws + 647168);
    __bf16* w4b = (__bf16*)(ws + 684032);

    cvt_bf16<<<(262144/4 + 255)/256, 256, 0, stream>>>(x,  xb,  262144/4);
    cvt_bf16<<<( 24576/4 + 255)/256, 256, 0, stream>>>(w1, w1b,  24576/4);
    cvt_bf16<<<( 36864/4 + 255)/256, 256, 0, stream>>>(w2, w2b,  36864/4);
    cvt_bf16<<<( 18432/4 + 255)/256, 256, 0, stream>>>(w3, w3b,  18432/4);
    cvt_bf16<<<(  9216/4 + 255)/256, 256, 0, stream>>>(w4, w4b,   9216/4);

    dim3 grid(NN / 16, NN / 4, NB);   // j-tiles, i-tiles, batch
    mlp_edges<<<grid, 256, 0, stream>>>(xb, w1b, b1, w2b, b2, w3b, b3, w4b, b4,
                                        w5, b5, out);

    softmax_rows<<<NB * NN, 256, 0, stream>>>(out);
}